// Round 2
// baseline (147.457 us; speedup 1.0000x reference)
//
#include <hip/hip_runtime.h>
#include <hip/hip_bf16.h>
#include <stdint.h>
#include <stddef.h>

constexpr int Bc = 2;
constexpr int Sc = 4096;
constexpr int Dc = 512;
constexpr int Hc = 8;
constexpr int Wc = 32;

using bf16_t = __bf16;
typedef __attribute__((ext_vector_type(8))) __bf16 bf16x8;
typedef __attribute__((ext_vector_type(4))) __bf16 bf16x4;
typedef __attribute__((ext_vector_type(2))) __bf16 bf16x2;
typedef __attribute__((ext_vector_type(4))) float f32x4;

__device__ __forceinline__ void async_copy16(const void* g, void* l) {
    __builtin_amdgcn_global_load_lds(
        (const __attribute__((address_space(1))) void*)g,
        (__attribute__((address_space(3))) void*)l,
        16, 0, 0);
}

// All input conversions in one launch (inputs are fp32 — measured round 7).
// Blocks 0..4095: x (4 elem/thread). Blocks 4096..5119: the 4 weights.
__global__ void convert_all(const float* __restrict__ x,
                            const float* __restrict__ wq, const float* __restrict__ wk,
                            const float* __restrict__ wv, const float* __restrict__ wo,
                            bf16_t* __restrict__ xc, bf16_t* __restrict__ dq,
                            bf16_t* __restrict__ dk, bf16_t* __restrict__ dv,
                            bf16_t* __restrict__ dwo) {
    const int blk = blockIdx.x;
    const float* s; bf16_t* d; int base;
    if (blk < 4096) { s = x; d = xc; base = blk * 1024; }
    else {
        const int r = blk - 4096, which = r >> 8;
        s = (which == 0) ? wq : (which == 1) ? wk : (which == 2) ? wv : wo;
        d = (which == 0) ? dq : (which == 1) ? dk : (which == 2) ? dv : dwo;
        base = (r & 255) * 1024;
    }
    const int i = base + threadIdx.x * 4;
    const float4 v = *(const float4*)(s + i);
    bf16x4 o; o[0] = (bf16_t)v.x; o[1] = (bf16_t)v.y;
    o[2] = (bf16_t)v.z; o[3] = (bf16_t)v.w;
    *(bf16x4*)(d + i) = o;
}

// C = A @ B^T (verified rounds 3-9). nPerB>0: virtual B=[B0;B1;B2].
template<int BM, int BN, int TM, int TN, bool F32OUT>
__global__ __launch_bounds__(256) void gemm_bt(
    const bf16_t* __restrict__ A, int lda,
    const bf16_t* __restrict__ B0, const bf16_t* __restrict__ B1,
    const bf16_t* __restrict__ B2, int ldb, int nPerB,
    void* __restrict__ C, int ldc, int K)
{
    constexpr int BK = 32;
    __shared__ __align__(1024) bf16_t Alds[BM * BK];
    __shared__ __align__(1024) bf16_t Blds[BN * BK];

    const int tid  = threadIdx.x;
    const int lane = tid & 63;
    const int wv   = tid >> 6;
    const int wm   = wv >> 1;
    const int wn   = wv & 1;
    const int r    = lane & 15;
    const int q4   = lane >> 4;

    const int blkM = blockIdx.x * BM;
    const int colC = blockIdx.y * BN;

    const bf16_t* Bp = B0;
    int nB = colC;
    if (nPerB > 0) {
        int wsel = colC / nPerB;
        nB = colC - wsel * nPerB;
        Bp = (wsel == 0) ? B0 : (wsel == 1) ? B1 : B2;
    }

    f32x4 acc[TM][TN];
    const f32x4 fzero = {0.f, 0.f, 0.f, 0.f};
    #pragma unroll
    for (int i = 0; i < TM; ++i)
        #pragma unroll
        for (int j = 0; j < TN; ++j) acc[i][j] = fzero;

    constexpr int A_LOADS = (BM * BK * 2) / (256 * 16);
    constexpr int B_LOADS = (BN * BK * 2) / (256 * 16);

    for (int kk = 0; kk < K; kk += BK) {
        __syncthreads();
        #pragma unroll
        for (int i = 0; i < A_LOADS; ++i) {
            int off  = i * 4096 + tid * 16;
            int row  = off >> 6;
            int colb = off & 63;
            const char* g = (const char*)A + ((size_t)(blkM + row) * lda + kk) * 2 + colb;
            async_copy16(g, (char*)Alds + off);
        }
        #pragma unroll
        for (int i = 0; i < B_LOADS; ++i) {
            int off  = i * 4096 + tid * 16;
            int row  = off >> 6;
            int colb = off & 63;
            const char* g = (const char*)Bp + ((size_t)(nB + row) * ldb + kk) * 2 + colb;
            async_copy16(g, (char*)Blds + off);
        }
        __syncthreads();

        bf16x8 af[TM], bfr[TN];
        #pragma unroll
        for (int mt = 0; mt < TM; ++mt)
            af[mt] = *(const bf16x8*)&Alds[(wm * TM * 16 + mt * 16 + r) * BK + q4 * 8];
        #pragma unroll
        for (int nt = 0; nt < TN; ++nt)
            bfr[nt] = *(const bf16x8*)&Blds[(wn * TN * 16 + nt * 16 + r) * BK + q4 * 8];

        #pragma unroll
        for (int mt = 0; mt < TM; ++mt)
            #pragma unroll
            for (int nt = 0; nt < TN; ++nt)
                acc[mt][nt] = __builtin_amdgcn_mfma_f32_16x16x32_bf16(
                    af[mt], bfr[nt], acc[mt][nt], 0, 0, 0);
    }

    #pragma unroll
    for (int mt = 0; mt < TM; ++mt) {
        #pragma unroll
        for (int nt = 0; nt < TN; ++nt) {
            int rr0 = blkM + wm * TM * 16 + mt * 16 + q4 * 4;
            int cc  = colC + wn * TN * 16 + nt * 16 + r;
            #pragma unroll
            for (int i = 0; i < 4; ++i) {
                size_t o = (size_t)(rr0 + i) * ldc + cc;
                if constexpr (F32OUT) ((float*)C)[o]  = acc[mt][nt][i];
                else                  ((bf16_t*)C)[o] = (bf16_t)acc[mt][nt][i];
            }
        }
    }
}

// Neighbor attention, one wave per (b,h,s) — register-only rewrite (round 10).
// Lane map: wq = lane>>3 (neighbor subgroup), d8 = lane&7 (dim octet).
// Per lane: 1x16B Q, 4x16B K, 4x16B V loads (each instr = 8 full 128B rows,
// contiguous). Softmax weights stay in the lanes that consume them in PV:
// no LDS, no __syncthreads, waves fully independent.
__global__ __launch_bounds__(256) void attn_fast(
    const bf16_t* __restrict__ QKV,
    const int*    __restrict__ nidx,
    bf16_t*       __restrict__ attn_out)
{
    const int lane = threadIdx.x & 63;
    const int wv   = threadIdx.x >> 6;

    // XCD swizzle: contiguous s-range per XCD for gather L2 locality.
    const int bi  = blockIdx.x;
    const int blk = (bi & 7) * 2048 + (bi >> 3);
    const int wg  = blk * 4 + wv;                  // ((b*8+h)<<12) + s
    const int s = wg & (Sc - 1);
    const int h = (wg >> 12) & (Hc - 1);
    const int b = wg >> 15;
    const size_t row = (size_t)b * Sc + s;

    const int d8 = lane & 7;                       // dims 8*d8 .. 8*d8+7
    const int wq = lane >> 3;                      // neighbors g*8 + wq

    const char* qkvB  = (const char*)QKV;
    const bf16x8 q8   = *(const bf16x8*)(qkvB + row * 3072 + h * 128 + d8 * 16);
    const char* Kbase = qkvB + (size_t)b * Sc * 3072 + 1024 + h * 128 + d8 * 16;
    const char* Vbase = qkvB + (size_t)b * Sc * 3072 + 2048 + h * 128 + d8 * 16;

    // Phase 1: 4 neighbors per lane-subgroup; K and V issued together so V's
    // latency hides under the dot/softmax.
    float  p[4];
    bf16x8 v8s[4];
    #pragma unroll
    for (int g = 0; g < 4; ++g) {
        const int t = nidx[s * Wc + g * 8 + wq];
        const size_t toff = (size_t)t * 3072;
        const bf16x8 k8 = *(const bf16x8*)(Kbase + toff);
        v8s[g] = *(const bf16x8*)(Vbase + toff);
        float d = 0.f;
        #pragma unroll
        for (int j = 0; j < 8; ++j) d += (float)q8[j] * (float)k8[j];
        // reduce across the 8 dim-octet lanes -> full 64-dim dot in each lane
        d += __shfl_xor(d, 1);
        d += __shfl_xor(d, 2);
        d += __shfl_xor(d, 4);
        p[g] = d * 0.125f;                         // 1/sqrt(64)
    }

    // Softmax over all 32 neighbors: local max/sum over g, butterfly over wq.
    float mx = fmaxf(fmaxf(p[0], p[1]), fmaxf(p[2], p[3]));
    mx = fmaxf(mx, __shfl_xor(mx, 8));
    mx = fmaxf(mx, __shfl_xor(mx, 16));
    mx = fmaxf(mx, __shfl_xor(mx, 32));
    float e[4];
    float sum = 0.f;
    #pragma unroll
    for (int g = 0; g < 4; ++g) { e[g] = __expf(p[g] - mx); sum += e[g]; }
    sum += __shfl_xor(sum, 8);
    sum += __shfl_xor(sum, 16);
    sum += __shfl_xor(sum, 32);
    const float inv = 1.0f / sum;

    // Phase 2: PV with weights already in-register in the right lanes.
    float acc[8] = {0.f, 0.f, 0.f, 0.f, 0.f, 0.f, 0.f, 0.f};
    #pragma unroll
    for (int g = 0; g < 4; ++g) {
        const float ag = e[g] * inv;
        #pragma unroll
        for (int j = 0; j < 8; ++j)
            acc[j] = fmaf(ag, (float)v8s[g][j], acc[j]);
    }
    // Reduce over the 8 neighbor-subgroups.
    #pragma unroll
    for (int j = 0; j < 8; ++j) {
        acc[j] += __shfl_xor(acc[j], 8);
        acc[j] += __shfl_xor(acc[j], 16);
        acc[j] += __shfl_xor(acc[j], 32);
    }
    if (wq == 0) {
        bf16x8 o;
        #pragma unroll
        for (int j = 0; j < 8; ++j) o[j] = (bf16_t)acc[j];
        *(bf16x8*)((char*)attn_out + row * 1024 + h * 128 + d8 * 16) = o;
    }
}

extern "C" void kernel_launch(void* const* d_in, const int* in_sizes, int n_in,
                              void* d_out, int out_size, void* d_ws, size_t ws_size,
                              hipStream_t stream) {
    (void)in_sizes; (void)n_in; (void)out_size; (void)ws_size;
    const int* nidx = (const int*)d_in[5];
    const int M = Bc * Sc;                        // 8192
    float* out = (float*)d_out;                   // fp32 output (round-7 finding)

    char* w = (char*)d_ws;
    bf16_t* xc   = (bf16_t*)(w + 256);            // 8 MB
    bf16_t* Wqc  = xc  + 4194304;                 // 0.5 MB each
    bf16_t* Wkc  = Wqc + 262144;
    bf16_t* Wvc  = Wkc + 262144;
    bf16_t* Woc  = Wvc + 262144;
    bf16_t* qkv  = Woc + 262144;                  // 24 MB
    bf16_t* attnS = xc;                           // reuse x-buffer after GEMM1

    convert_all<<<5120, 256, 0, stream>>>(
        (const float*)d_in[0], (const float*)d_in[1], (const float*)d_in[2],
        (const float*)d_in[3], (const float*)d_in[4],
        xc, Wqc, Wkc, Wvc, Woc);

    // Fused QKV projection: M=8192, N=1536, K=512 (bf16 out).
    gemm_bt<128, 128, 4, 4, false><<<dim3(M / 128, 1536 / 128), 256, 0, stream>>>(
        xc, Dc, Wqc, Wkc, Wvc, Dc, 512, qkv, 1536, Dc);

    // Neighbor attention (register-only, no LDS/barrier).
    attn_fast<<<(Bc * Hc * Sc) / 4, 256, 0, stream>>>(qkv, nidx, attnS);

    // Output projection: M=8192, N=512, K=512 -> fp32 d_out.
    // Dense 128x128 tile (verified config), grid 64x4 = 256 blocks = exact CU fit.
    gemm_bt<128, 128, 4, 4, true><<<dim3(M / 128, 512 / 128), 256, 0, stream>>>(
        attnS, 512, Woc, Woc, Woc, 512, 0, out, Dc, Dc);
}